// Round 1
// baseline (2682.564 us; speedup 1.0000x reference)
//
#include <hip/hip_runtime.h>
#include <math.h>

#define MDIM 4096
#define LR 0.1f
#define B1 0.9f
#define B2 0.999f
#define EPS 1e-8f

// ---------------------------------------------------------------------------
// Prep: Qs[i][j] = 0.5*(va[i][j] + va[j][i]), LDS-tiled so both reads coalesce.
// Grid: (128,128) blocks of (32,8).
// ---------------------------------------------------------------------------
__global__ void prep_qs(const float* __restrict__ va, float* __restrict__ Qs) {
    __shared__ float tile[32][33];  // +1 pad: avoid bank conflicts on transposed read
    const int j0 = blockIdx.x * 32;   // col-tile origin of the OUTPUT block
    const int i0 = blockIdx.y * 32;   // row-tile origin of the OUTPUT block
    const int tx = threadIdx.x;       // 0..31
    const int ty = threadIdx.y;       // 0..7

    // Load mirror tile: va[j0..j0+31][i0..i0+31] (coalesced rows)
    for (int k = 0; k < 32; k += 8) {
        int r = j0 + ty + k;
        tile[ty + k][tx] = va[(size_t)r * MDIM + i0 + tx];
    }
    __syncthreads();

    // Output rows i0..i0+31, cols j0..j0+31 (coalesced)
    for (int k = 0; k < 32; k += 8) {
        int i = i0 + ty + k;
        float a = va[(size_t)i * MDIM + j0 + tx];
        float b = tile[tx][ty + k];  // = va[j0+tx][i0+ty+k] = va[j][i]
        Qs[(size_t)i * MDIM + j0 + tx] = 0.5f * (a + b);
    }
}

// ---------------------------------------------------------------------------
// Init: u = 1 - mean (state in u = w - mean space), mt = vt = 0.
// ---------------------------------------------------------------------------
__global__ void init_state(const float* __restrict__ mean,
                           float* __restrict__ u,
                           float* __restrict__ mt,
                           float* __restrict__ vt) {
    int i = blockIdx.x * blockDim.x + threadIdx.x;
    if (i < MDIM) {
        u[i]  = 1.0f - mean[i];
        mt[i] = 0.0f;
        vt[i] = 0.0f;
    }
}

// ---------------------------------------------------------------------------
// One Adam step:  g = Qs @ u_in ;  mt,vt update ;  u_out = u_in - lr/bc1 * ...
// 256 blocks x 1024 threads. Block b owns rows [16b, 16b+16); wave k -> one row.
// Full u_in staged in LDS (16 KB). Row-dot: float4 loads, butterfly reduce.
// Scalars (LR/bc1, 1/sqrt(bc2)) computed on host in double per step t.
// Also writes w = u_out + mean to d_out every step (last step wins).
// ---------------------------------------------------------------------------
__global__ __launch_bounds__(1024) void adam_step(
        const float* __restrict__ Qs,
        const float* __restrict__ u_in,
        float* __restrict__ u_out,
        float* __restrict__ mt,
        float* __restrict__ vt,
        const float* __restrict__ mean,
        float* __restrict__ w_out,
        float lr_over_bc1,
        float inv_sqrt_bc2) {
    __shared__ float su[MDIM];

    const int tid = threadIdx.x;
    // Stage full u vector into LDS: 1024 threads x float4 = 4096 floats.
    float4* su4 = (float4*)su;
    const float4* u4 = (const float4*)u_in;
    su4[tid] = u4[tid];
    __syncthreads();

    const int wave = tid >> 6;
    const int lane = tid & 63;
    const int row  = blockIdx.x * 16 + wave;

    const float4* qrow = (const float4*)(Qs + (size_t)row * MDIM);
    float acc = 0.0f;
#pragma unroll
    for (int it = 0; it < 16; ++it) {
        float4 q = qrow[lane + 64 * it];
        float4 u = su4[lane + 64 * it];
        acc += q.x * u.x + q.y * u.y + q.z * u.z + q.w * u.w;
    }
    // Butterfly reduce across the 64-lane wave (all lanes end with the sum).
#pragma unroll
    for (int off = 32; off > 0; off >>= 1) acc += __shfl_xor(acc, off);
    const float g = acc;

    // Adam update for this row (all lanes compute identically; lane 0 stores).
    const float m_old = mt[row];
    const float v_old = vt[row];
    const float m_new = B1 * m_old + (1.0f - B1) * g;
    const float v_new = B2 * v_old + (1.0f - B2) * g * g;
    const float denom = sqrtf(v_new) * inv_sqrt_bc2 + EPS;
    const float u_new = su[row] - lr_over_bc1 * m_new / denom;

    if (lane == 0) {
        mt[row]   = m_new;
        vt[row]   = v_new;
        u_out[row] = u_new;
        w_out[row] = u_new + mean[row];
    }
}

extern "C" void kernel_launch(void* const* d_in, const int* in_sizes, int n_in,
                              void* d_out, int out_size, void* d_ws, size_t ws_size,
                              hipStream_t stream) {
    const float* mean = (const float*)d_in[0];   // (4096,)
    const float* va   = (const float*)d_in[1];   // (4096,4096)
    // d_in[2] = xt, unused by the reference.
    float* w_out = (float*)d_out;                // (4096,)

    float* ws = (float*)d_ws;
    float* Qs = ws;                                   // 16M floats = 64 MB
    float* u0 = ws + (size_t)MDIM * MDIM;             // 4096
    float* u1 = u0 + MDIM;                            // 4096
    float* mt = u1 + MDIM;                            // 4096
    float* vt = mt + MDIM;                            // 4096

    prep_qs<<<dim3(MDIM / 32, MDIM / 32), dim3(32, 8), 0, stream>>>(va, Qs);
    init_state<<<(MDIM + 255) / 256, 256, 0, stream>>>(mean, u0, mt, vt);

    float* u_in  = u0;
    float* u_out = u1;
    for (int t = 1; t <= 199; ++t) {
        const double bc1 = 1.0 - pow(0.9, (double)t);
        const double bc2 = 1.0 - pow(0.999, (double)t);
        const float lr_over_bc1 = (float)(0.1 / bc1);
        const float inv_sqrt_bc2 = (float)(1.0 / sqrt(bc2));
        adam_step<<<MDIM / 16, 1024, 0, stream>>>(Qs, u_in, u_out, mt, vt, mean,
                                                  w_out, lr_over_bc1, inv_sqrt_bc2);
        float* tmp = u_in; u_in = u_out; u_out = tmp;
    }
}

// Round 3
// 1158.468 us; speedup vs baseline: 2.3156x; 2.3156x over previous
//
#include <hip/hip_runtime.h>
#include <math.h>

#define MDIM   4096
#define NSTEPS 199
#define NBLK   256     // one block per CU
#define NTHR   1024    // 16 waves; wave w owns row bid*16+w
#define B1C    0.9f
#define B2C    0.999f
#define EPSC   1e-8f

// ---------------------------------------------------------------------------
// Prep: Qs[i][j] = 0.5*(va[i][j] + va[j][i]), LDS-tiled transpose (validated R1).
// ---------------------------------------------------------------------------
__global__ void prep_qs(const float* __restrict__ va, float* __restrict__ Qs) {
    __shared__ float tile[32][33];
    const int j0 = blockIdx.x * 32;
    const int i0 = blockIdx.y * 32;
    const int tx = threadIdx.x, ty = threadIdx.y;

    for (int k = 0; k < 32; k += 8)
        tile[ty + k][tx] = va[(size_t)(j0 + ty + k) * MDIM + i0 + tx];
    __syncthreads();
    for (int k = 0; k < 32; k += 8) {
        int i = i0 + ty + k;
        float a = va[(size_t)i * MDIM + j0 + tx];
        float b = tile[tx][ty + k];          // va[j][i]
        Qs[(size_t)i * MDIM + j0 + tx] = 0.5f * (a + b);
    }
}

// ---------------------------------------------------------------------------
// Init: u0 = 1 - mean; zero the barrier flag array.
// ---------------------------------------------------------------------------
__global__ void init_state(const float* __restrict__ mean,
                           float* __restrict__ u0,
                           int* __restrict__ flags, int nflags) {
    int i = blockIdx.x * blockDim.x + threadIdx.x;
    if (i < MDIM)   u0[i] = 1.0f - mean[i];
    if (i < nflags) flags[i] = 0;
}

// ---------------------------------------------------------------------------
// Persistent cooperative kernel, fp32 end-to-end.
// Wave w of block b owns row r=16b+w. Its Q row (4096 fp32) lives in
// 64 VGPRs/lane (float4 qreg[16]) loaded ONCE -> zero per-step Q traffic.
// Per step: coherent-stage u into LDS, reg-dot, butterfly reduce, Adam
// (m/v in registers), publish u[row] (agent-scope write-through), flag-array
// grid barrier (relaxed agent atomics; no acquire fences -> nothing ever
// invalidates caches).
// ---------------------------------------------------------------------------
__global__ __launch_bounds__(NTHR) void adam_persist(
        const float* __restrict__ Qs,
        float* u0, float* u1,
        const float* __restrict__ mean,
        float* __restrict__ w_out,
        int* __restrict__ flags) {
    __shared__ float su[MDIM];
    float4* su4 = (float4*)su;

    const int tid  = threadIdx.x;
    const int bid  = blockIdx.x;
    const int wave = tid >> 6;
    const int lane = tid & 63;
    const int row  = bid * 16 + wave;

    // ---- one-time: Q row -> registers (64 VGPRs/lane) ----
    float4 qreg[16];
    const float4* qrow4 = (const float4*)(Qs + (size_t)row * MDIM);
#pragma unroll
    for (int it = 0; it < 16; ++it) qreg[it] = qrow4[lane + 64 * it];

    float m = 0.0f, v = 0.0f, b1p = 1.0f, b2p = 1.0f, unew = 0.0f;

    for (int t = 1; t <= NSTEPS; ++t) {
        const float* uin  = (t & 1) ? u0 : u1;   // t=1 reads u0
        float*       uout = (t & 1) ? u1 : u0;

        // ---- stage u into LDS (agent-coherent loads bypass stale L2) ----
#pragma unroll
        for (int k = 0; k < 4; ++k) {
            int idx = tid + NTHR * k;
            su[idx] = __hip_atomic_load(uin + idx, __ATOMIC_RELAXED,
                                        __HIP_MEMORY_SCOPE_AGENT);
        }
        __syncthreads();

        // ---- row dot from registers ----
        float acc = 0.0f;
#pragma unroll
        for (int it = 0; it < 16; ++it) {
            float4 q = qreg[it];
            float4 u = su4[lane + 64 * it];
            acc += q.x * u.x + q.y * u.y + q.z * u.z + q.w * u.w;
        }
#pragma unroll
        for (int off = 32; off > 0; off >>= 1) acc += __shfl_xor(acc, off);
        const float g = acc;

        // ---- Adam update (state in registers, replicated across lanes) ----
        b1p *= B1C;
        b2p *= B2C;
        m = B1C * m + (1.0f - B1C) * g;
        v = B2C * v + (1.0f - B2C) * g * g;
        const float denom = sqrtf(v) / sqrtf(1.0f - b2p) + EPSC;
        unew = su[row] - (0.1f / (1.0f - b1p)) * m / denom;

        if (lane == 0)
            __hip_atomic_store(uout + row, unew, __ATOMIC_RELAXED,
                               __HIP_MEMORY_SCOPE_AGENT);
        // syncthreads drains the store (s_waitcnt vmcnt(0) before s_barrier)
        // -> release ordering for the flag below.
        __syncthreads();

        if (tid == 0)
            __hip_atomic_store(flags + t * NBLK + bid, 1, __ATOMIC_RELAXED,
                               __HIP_MEMORY_SCOPE_AGENT);

        // ---- grid barrier: wave 0 polls all 256 per-block flags ----
        if (tid < 64) {
            const int* f = flags + t * NBLK + 4 * tid;
            int spin = 0;
            for (;;) {
                int s0 = __hip_atomic_load(f + 0, __ATOMIC_RELAXED, __HIP_MEMORY_SCOPE_AGENT);
                int s1 = __hip_atomic_load(f + 1, __ATOMIC_RELAXED, __HIP_MEMORY_SCOPE_AGENT);
                int s2 = __hip_atomic_load(f + 2, __ATOMIC_RELAXED, __HIP_MEMORY_SCOPE_AGENT);
                int s3 = __hip_atomic_load(f + 3, __ATOMIC_RELAXED, __HIP_MEMORY_SCOPE_AGENT);
                if ((s0 & s1 & s2 & s3) != 0) break;
                if (++spin > (1 << 25)) break;   // fail visibly, never hang
            }
        }
        __syncthreads();
    }

    if (lane == 0) w_out[row] = unew + mean[row];
}

extern "C" void kernel_launch(void* const* d_in, const int* in_sizes, int n_in,
                              void* d_out, int out_size, void* d_ws, size_t ws_size,
                              hipStream_t stream) {
    const float* mean = (const float*)d_in[0];   // (4096,)
    const float* va   = (const float*)d_in[1];   // (4096,4096)
    float* w_out = (float*)d_out;                // (4096,)

    float* ws = (float*)d_ws;
    float* Qs  = ws;                              // 64 MB
    float* u0  = ws + (size_t)MDIM * MDIM;        // 16 KB
    float* u1  = u0 + MDIM;                       // 16 KB
    int*   flg = (int*)(u1 + MDIM);               // (NSTEPS+1)*256 ints

    const int nflags = (NSTEPS + 1) * NBLK;

    prep_qs<<<dim3(MDIM / 32, MDIM / 32), dim3(32, 8), 0, stream>>>(va, Qs);
    init_state<<<(nflags + 255) / 256, 256, 0, stream>>>(mean, u0, flg, nflags);

    void* args[] = { (void*)&Qs, (void*)&u0, (void*)&u1,
                     (void*)&mean, (void*)&w_out, (void*)&flg };
    hipLaunchCooperativeKernel((const void*)adam_persist,
                               dim3(NBLK), dim3(NTHR), args, 0, stream);
}